// Round 6
// baseline (988.325 us; speedup 1.0000x reference)
//
#include <hip/hip_runtime.h>
#include <math.h>

// AxialLinearAttention — fp16 MFMA GEMMs (256x128 tile, 3-deep pipelined LDS,
// counted vmcnt across raw barriers) + (QK^T)V linattn.
// B=256, FG=4, ANT=32, D=1024, H=16, DK=64. M = 32768 rows for every GEMM.
// Scale bookkeeping (all powers of 2, exact):
//   xh = x (fp16, scale 1); Q1,K1,V1 scale 1; att1 stored * 2^-4
//   X2h = X2 * 2^-4 (fp16, overwrites xh in place); Q2,K2,V2 stored * 2^-4
//   att2 stored * 2^-16; final out = 2^16 * acc + bias + 16 * X2h  (fp32)

#define MTOT 32768
#define DM 1024

using half8   = __attribute__((ext_vector_type(8))) _Float16;
using h2      = __attribute__((ext_vector_type(2))) _Float16;
using floatx4 = __attribute__((ext_vector_type(4))) float;

#define ACT_NONE 0
#define ACT_ELU1 1
#define REMAP_NONE 0
#define REMAP_A2F 1   // (b,fg,ant) -> (b,ant,fg)
#define REMAP_F2O 2   // (b,ant,fg) -> (b,fg,ant)

#define VMWAIT(n) asm volatile("s_waitcnt vmcnt(" #n ")" ::: "memory")
#define SBAR() do { __builtin_amdgcn_s_barrier(); \
                    __builtin_amdgcn_sched_barrier(0); } while (0)

__device__ __forceinline__ void gload16(const void* g, void* ldsp) {
  __builtin_amdgcn_global_load_lds(
      (const __attribute__((address_space(1))) unsigned int*)g,
      (__attribute__((address_space(3))) unsigned int*)ldsp, 16, 0, 0);
}

__device__ __forceinline__ float fdot2f(h2 a, h2 b, float c) {
#if __has_builtin(__builtin_amdgcn_fdot2)
  return __builtin_amdgcn_fdot2(a, b, c, false);
#else
  return fmaf((float)a[0], (float)b[0], fmaf((float)a[1], (float)b[1], c));
#endif
}

// ---------------- GEMM ----------------
// C = act(sin_s * (A @ Wt^T) + bias [+ rs*resid16]); rows remapped on store.
// A: [M][1024] fp16 K-major. Wt: [N][1024] fp16 K-major (pre-transposed W).
// 256x128 tile, BK=64, 512 threads (8 waves 4Mx2N, wave -> 64x64 = 4x4 frags).
// LDS: 3-slot ring, slot = K-step%3. A-slot 256x64 (32KB), B-slot 128x64 (16KB),
// total 144KB -> 1 block/CU. Pipeline: at step t issue stage(t+2), then
// s_waitcnt vmcnt(12) (2 steps x 6 loads stay in flight) + raw s_barrier,
// compute step t, raw s_barrier. Rows are 128B = 8 x 16B slots; swizzle
// slot ^= row&7 via pre-swizzled global source (linear LDS dest) + XOR on
// the ds_read address; 16-lane frag reads hit each bank-quad 2x (free).
template<int ACT, int REMAP, bool RES, bool OF32, bool OF16>
__global__ __launch_bounds__(512, 2) void gemm_k(
    const _Float16* __restrict__ A, const _Float16* __restrict__ W,
    const float* __restrict__ bias, const _Float16* __restrict__ resid,
    float rs, float* __restrict__ Cf, _Float16* __restrict__ Ch,
    float sin_s, float sout_s)
{
  __shared__ __align__(16) char lds[147456];  // 3x32KB A | 3x16KB B

  const int t = threadIdx.x, w = t >> 6, l = t & 63;
  // XCD-aware bijective swizzle of the m-tile index (gridDim.x = 128, %8 == 0)
  const int bx = blockIdx.x;
  const int m0 = (((bx & 7) << 4) + (bx >> 3)) * 256;
  const int n0 = blockIdx.y * 128;
  const int lr = l & 15, ls = l >> 4;
  const int wrow = (w >> 1) * 64, wcol = (w & 1) * 64;

  // staging geometry: element e = i*512 + t; row = e>>3 = i*64 + (t>>3);
  // slot = l&7; global fetch k-slot = slot ^ (row&7) (row&7 == (t>>3)&7).
  const int trow = t >> 3;                       // 0..63
  const int tsk  = ((t & 7) ^ (trow & 7)) * 8;   // swizzled k offset (halves)
  char* const ldsw = lds + w * 1024;             // wave chunk base for gload

  // ds_read byte offsets within a slot (k-step-independent)
  int aoff[2][4], boff[2][4];
#pragma unroll
  for (int kk = 0; kk < 2; ++kk)
#pragma unroll
    for (int m = 0; m < 4; ++m) {
      int ra = wrow + m * 16 + lr;               // 0..255
      aoff[kk][m] = ra * 128 + (((kk * 4 + ls) ^ (ra & 7)) << 4);
      int rb = wcol + m * 16 + lr;               // 0..127
      boff[kk][m] = rb * 128 + (((kk * 4 + ls) ^ (rb & 7)) << 4);
    }

  floatx4 acc[4][4];
#pragma unroll
  for (int m = 0; m < 4; ++m)
#pragma unroll
    for (int n = 0; n < 4; ++n) acc[m][n] = (floatx4)0.f;

  auto stage = [&](int kt, int p) {  // 6 gload_lds: A 4, B 2
    const int kb = kt * 64;
#pragma unroll
    for (int i = 0; i < 4; ++i)
      gload16(A + (size_t)(m0 + i * 64 + trow) * DM + kb + tsk,
              ldsw + p * 32768 + i * 8192);
#pragma unroll
    for (int i = 0; i < 2; ++i)
      gload16(W + (size_t)(n0 + i * 64 + trow) * DM + kb + tsk,
              ldsw + 98304 + p * 16384 + i * 8192);
  };

  auto compute = [&](int p) {
    const char* Ab = lds + p * 32768;
    const char* Bb = lds + 98304 + p * 16384;
#pragma unroll
    for (int kk = 0; kk < 2; ++kk) {
      half8 af[4], bf[4];
#pragma unroll
      for (int m = 0; m < 4; ++m) af[m] = *(const half8*)(Ab + aoff[kk][m]);
#pragma unroll
      for (int n = 0; n < 4; ++n) bf[n] = *(const half8*)(Bb + boff[kk][n]);
      __builtin_amdgcn_s_setprio(1);
#pragma unroll
      for (int m = 0; m < 4; ++m)
#pragma unroll
        for (int n = 0; n < 4; ++n)
          acc[m][n] =
              __builtin_amdgcn_mfma_f32_16x16x32_f16(af[m], bf[n], acc[m][n], 0, 0, 0);
      __builtin_amdgcn_s_setprio(0);
    }
  };

  // prologue: stage K-steps 0,1
  stage(0, 0);
  stage(1, 1);
  // main: K = 1024 -> 16 K-steps
  for (int t2 = 0; t2 < 14; ++t2) {
    stage(t2 + 2, (t2 + 2) % 3);
    VMWAIT(12);   // 2 steps x 6 loads stay in flight; step t2 fully in LDS
    SBAR();
    compute(t2 % 3);
    SBAR();       // all reads of slot t2%3 done before it is restaged
  }
  VMWAIT(6);  SBAR(); compute(2); SBAR();
  VMWAIT(0);  SBAR(); compute(0);

  // hoist bias (4 distinct values per thread)
  float bb[4];
#pragma unroll
  for (int n = 0; n < 4; ++n) bb[n] = bias[n0 + wcol + n * 16 + lr];

  // epilogue phase 1: finalize values in acc (C/D map: row=(l>>4)*4+j, col=l&15)
#pragma unroll
  for (int m = 0; m < 4; ++m)
#pragma unroll
    for (int n = 0; n < 4; ++n)
#pragma unroll
      for (int j = 0; j < 4; ++j) {
        int rt = wrow + m * 16 + ls * 4 + j;
        int ct = wcol + n * 16 + lr;
        float v = acc[m][n][j] * sin_s + bb[n];
        if (RES) v += rs * (float)resid[(size_t)(m0 + rt) * DM + n0 + ct];
        if (ACT == ACT_ELU1) v = (v > 0.f) ? (v + 1.f) : expf(v);
        acc[m][n][j] = v;
      }
  // order all resid reads before any (possibly in-place, row-permuted) store
  if (RES && REMAP != REMAP_NONE) __syncthreads();

#pragma unroll
  for (int m = 0; m < 4; ++m)
#pragma unroll
    for (int n = 0; n < 4; ++n)
#pragma unroll
      for (int j = 0; j < 4; ++j) {
        int rt = wrow + m * 16 + ls * 4 + j;
        int ct = wcol + n * 16 + lr;
        int mg = m0 + rt, ng = n0 + ct;
        int srw;
        if (REMAP == REMAP_NONE) {
          srw = mg;
        } else if (REMAP == REMAP_A2F) {
          int b = mg >> 7, fg = (mg >> 5) & 3, ant = mg & 31;
          srw = b * 128 + ant * 4 + fg;
        } else {
          int b = mg >> 7, ant = (mg >> 2) & 31, fg = mg & 3;
          srw = b * 128 + fg * 32 + ant;
        }
        float v = acc[m][n][j];
        if (OF32) Cf[(size_t)srw * DM + ng] = v;
        if (OF16) Ch[(size_t)srw * DM + ng] = (_Float16)(v * sout_s);
      }
}

// ---------------- stage-1 linattn: L=32, one block per (g,h) ----------------
__global__ __launch_bounds__(256) void linattn32_k(
    _Float16* __restrict__ Q, const _Float16* __restrict__ K,
    const _Float16* __restrict__ V, float sout)
{
  __shared__ _Float16 Qs[32][64];   // swizzled: chunk ^= (row&7)*8
  __shared__ _Float16 Ks[32][64];   // swizzled: chunk ^= ((row>>2)&7)*8
  __shared__ _Float16 Vs[32][64];   // linear
  __shared__ float Ss[32][33];

  const int g = blockIdx.x, h = blockIdx.y;
  const size_t base = (size_t)g * 32 * DM + h * 64;
  const int t = threadIdx.x;

  {
    const int row = t >> 3, ch = (t & 7) * 8;
    half8 q8 = *(const half8*)(Q + base + (size_t)row * DM + ch);
    half8 k8 = *(const half8*)(K + base + (size_t)row * DM + ch);
    half8 v8 = *(const half8*)(V + base + (size_t)row * DM + ch);
    *(half8*)&Qs[row][ch ^ ((row & 7) * 8)] = q8;
    *(half8*)&Ks[row][ch ^ (((row >> 2) & 7) * 8)] = k8;
    *(half8*)&Vs[row][ch] = v8;
  }
  __syncthreads();

  {  // S[t][s] = Q[t] . K[s] ; thread -> (tt, 4 s's)
    const int tt = t >> 3, sg = t & 7;
    const int xq = (tt & 7) * 8, xk = sg * 8;
    float acc[4] = {};
#pragma unroll
    for (int jj = 0; jj < 32; ++jj) {
      h2 qq = *(const h2*)&Qs[tt][(2 * jj) ^ xq];
#pragma unroll
      for (int si = 0; si < 4; ++si) {
        h2 kk = *(const h2*)&Ks[sg * 4 + si][(2 * jj) ^ xk];
        acc[si] = fdot2f(qq, kk, acc[si]);
      }
    }
#pragma unroll
    for (int si = 0; si < 4; ++si) Ss[tt][sg * 4 + si] = acc[si];
  }
  __syncthreads();

  {  // att[t][e] = sum_s S[t][s] V[s][e] ; thread -> (tt, 8 e's)
    const int tt = t >> 3, e0 = (t & 7) * 8;
    float o[8] = {};
#pragma unroll
    for (int s = 0; s < 32; ++s) {
      float sv = Ss[tt][s];
      half8 vv = *(const half8*)&Vs[s][e0];
#pragma unroll
      for (int e = 0; e < 8; ++e) o[e] = fmaf(sv, (float)vv[e], o[e]);
    }
    half8 r;
#pragma unroll
    for (int e = 0; e < 8; ++e) r[e] = (_Float16)(o[e] * sout);
    *(half8*)(Q + base + (size_t)tt * DM + e0) = r;
  }
}

// ---------------- stage-2 linattn: L=4, one block per batch (16 heads) -------
__global__ __launch_bounds__(256) void linattn4_k(
    _Float16* __restrict__ Q, const _Float16* __restrict__ K,
    const _Float16* __restrict__ V, float sout)
{
  __shared__ _Float16 Qs[4][1024];  // per-head swizzle: chunk ^= (h&7)*8
  __shared__ _Float16 Ks[4][1024];
  __shared__ _Float16 Vs[4][1024];
  __shared__ float Ss[16][4][5];

  const int g = blockIdx.x;
  const size_t base = (size_t)g * 4 * DM;
  const int t = threadIdx.x;

  {
    const int off = t * 16;
    const int row = off >> 10, col = off & 1023;
    const int h = col >> 6, d = col & 63, x = (h & 7) * 8;
    const int c0 = h * 64 + (d ^ x), c1 = h * 64 + ((d + 8) ^ x);
    half8 q0 = *(const half8*)(Q + base + off);
    half8 q1 = *(const half8*)(Q + base + off + 8);
    half8 k0 = *(const half8*)(K + base + off);
    half8 k1 = *(const half8*)(K + base + off + 8);
    half8 v0 = *(const half8*)(V + base + off);
    half8 v1 = *(const half8*)(V + base + off + 8);
    *(half8*)&Qs[row][c0] = q0; *(half8*)&Qs[row][c1] = q1;
    *(half8*)&Ks[row][c0] = k0; *(half8*)&Ks[row][c1] = k1;
    *(half8*)&Vs[row][c0] = v0; *(half8*)&Vs[row][c1] = v1;
  }
  __syncthreads();

  {  // S[h][t][s]: one 64-dot per thread
    const int h = t >> 4, tt = (t >> 2) & 3, s = t & 3;
    const int x = (h & 7) * 8;
    const _Float16* qp = &Qs[tt][h * 64];
    const _Float16* kp = &Ks[s][h * 64];
    float acc = 0.f;
#pragma unroll
    for (int jj = 0; jj < 32; ++jj) {
      int dd = (2 * jj) ^ x;
      acc = fdot2f(*(const h2*)(qp + dd), *(const h2*)(kp + dd), acc);
    }
    Ss[h][tt][s] = acc;
  }
  __syncthreads();

  {  // att[t][h*64+e] = sum_s S[h][t][s] V[s][h*64+e] ; thread -> 16 cols
    const int tt = t >> 6, cg = t & 63;
    const int h = cg >> 2, e0 = (cg & 3) * 16, x = (h & 7) * 8;
    const float* sp = Ss[h][tt];
    float o[16] = {};
#pragma unroll
    for (int s = 0; s < 4; ++s) {
      float sv = sp[s];
      half8 va = *(const half8*)&Vs[s][h * 64 + (e0 ^ x)];
      half8 vb = *(const half8*)&Vs[s][h * 64 + ((e0 + 8) ^ x)];
#pragma unroll
      for (int e = 0; e < 8; ++e) {
        o[e]     = fmaf(sv, (float)va[e], o[e]);
        o[e + 8] = fmaf(sv, (float)vb[e], o[e + 8]);
      }
    }
    half8 r0, r1;
#pragma unroll
    for (int e = 0; e < 8; ++e) {
      r0[e] = (_Float16)(o[e] * sout);
      r1[e] = (_Float16)(o[e + 8] * sout);
    }
    _Float16* dst = Q + base + (size_t)tt * DM + h * 64 + e0;
    *(half8*)dst = r0;
    *(half8*)(dst + 8) = r1;
  }
}

// ---------------- small prep kernels ----------------
struct WPtrs { const float* p[8]; };

__global__ __launch_bounds__(256) void transpose_w8_k(
    WPtrs ws, _Float16* __restrict__ wt)
{
  __shared__ float tile[32][33];
  const float* W = ws.p[blockIdx.z];
  _Float16* Wt = wt + (size_t)DM * DM * blockIdx.z;
  const int tx = threadIdx.x & 31, ty = threadIdx.x >> 5;
  const int k0 = blockIdx.x * 32, n0 = blockIdx.y * 32;
#pragma unroll
  for (int r = 0; r < 4; ++r)
    tile[ty + r * 8][tx] = W[(size_t)(k0 + ty + r * 8) * DM + n0 + tx];
  __syncthreads();
#pragma unroll
  for (int r = 0; r < 4; ++r)
    Wt[(size_t)(n0 + ty + r * 8) * DM + k0 + tx] = (_Float16)tile[tx][ty + r * 8];
}

__global__ __launch_bounds__(256) void convf2h_k(
    const float* __restrict__ x, _Float16* __restrict__ xh, int n8)
{
  for (int i = blockIdx.x * blockDim.x + threadIdx.x; i < n8;
       i += gridDim.x * blockDim.x) {
    float4 a = ((const float4*)x)[i * 2];
    float4 b = ((const float4*)x)[i * 2 + 1];
    half8 h;
    h[0] = (_Float16)a.x; h[1] = (_Float16)a.y; h[2] = (_Float16)a.z; h[3] = (_Float16)a.w;
    h[4] = (_Float16)b.x; h[5] = (_Float16)b.y; h[6] = (_Float16)b.z; h[7] = (_Float16)b.w;
    ((half8*)xh)[i] = h;
  }
}

extern "C" void kernel_launch(void* const* d_in, const int* in_sizes, int n_in,
                              void* d_out, int out_size, void* d_ws, size_t ws_size,
                              hipStream_t stream)
{
  const float* x   = (const float*)d_in[0];
  WPtrs wp;
  for (int j = 0; j < 8; ++j) wp.p[j] = (const float*)d_in[1 + 2 * j];
  const float* aqb = (const float*)d_in[2];  const float* akb = (const float*)d_in[4];
  const float* avb = (const float*)d_in[6];  const float* aob = (const float*)d_in[8];
  const float* fqb = (const float*)d_in[10]; const float* fkb = (const float*)d_in[12];
  const float* fvb = (const float*)d_in[14]; const float* fob = (const float*)d_in[16];
  float* out = (float*)d_out;

  const size_t NE = (size_t)MTOT * DM;
  _Float16* xh = (_Float16*)d_ws;     // holds x, then X2h (in-place remap)
  _Float16* Qh = xh + NE;             // att overwrites Q in place
  _Float16* Kh = Qh + NE;
  _Float16* Vh = Kh + NE;
  _Float16* wt = Vh + NE;             // 8 x 1M halves
  const size_t WSZ = (size_t)DM * DM;

  dim3 gg(MTOT / 256, DM / 128), gb(512), sb(256);

  convf2h_k<<<2048, sb, 0, stream>>>(x, xh, (int)(NE / 8));
  transpose_w8_k<<<dim3(32, 32, 8), sb, 0, stream>>>(wp, wt);

  const float S = 0.0625f;  // 2^-4

  // ----- stage 1: antenna attention -----
  gemm_k<ACT_ELU1, REMAP_NONE, false, false, true><<<gg, gb, 0, stream>>>(
      xh, wt + WSZ * 0, aqb, nullptr, 0.f, nullptr, Qh, 1.f, 1.f);
  gemm_k<ACT_ELU1, REMAP_NONE, false, false, true><<<gg, gb, 0, stream>>>(
      xh, wt + WSZ * 1, akb, nullptr, 0.f, nullptr, Kh, 1.f, 1.f);
  gemm_k<ACT_NONE, REMAP_NONE, false, false, true><<<gg, gb, 0, stream>>>(
      xh, wt + WSZ * 2, avb, nullptr, 0.f, nullptr, Vh, 1.f, 1.f);
  linattn32_k<<<dim3(1024, 16), sb, 0, stream>>>(Qh, Kh, Vh, S);
  // X2h = (x + att1*2^4 @ Wout) * 2^-4, rows -> (b,ant,fg), in place over xh
  gemm_k<ACT_NONE, REMAP_A2F, true, false, true><<<gg, gb, 0, stream>>>(
      Qh, wt + WSZ * 3, aob, xh, 1.f, nullptr, xh, 16.f, S);

  // ----- stage 2: frequency attention -----
  gemm_k<ACT_ELU1, REMAP_NONE, false, false, true><<<gg, gb, 0, stream>>>(
      xh, wt + WSZ * 4, fqb, nullptr, 0.f, nullptr, Qh, 16.f, S);
  gemm_k<ACT_ELU1, REMAP_NONE, false, false, true><<<gg, gb, 0, stream>>>(
      xh, wt + WSZ * 5, fkb, nullptr, 0.f, nullptr, Kh, 16.f, S);
  gemm_k<ACT_NONE, REMAP_NONE, false, false, true><<<gg, gb, 0, stream>>>(
      xh, wt + WSZ * 6, fvb, nullptr, 0.f, nullptr, Vh, 16.f, S);
  linattn4_k<<<8192, sb, 0, stream>>>(Qh, Kh, Vh, S);
  // out = 2^16 * (att2 @ Wout2) + bias + 16*X2h, rows back to (b,fg,ant), fp32
  gemm_k<ACT_NONE, REMAP_F2O, true, true, false><<<gg, gb, 0, stream>>>(
      Qh, wt + WSZ * 7, fob, xh, 16.f, out, nullptr, 65536.f, 1.f);
}

// Round 7
// 834.638 us; speedup vs baseline: 1.1841x; 1.1841x over previous
//
#include <hip/hip_runtime.h>
#include <math.h>

// AxialLinearAttention — fp16 MFMA GEMMs (256x256 tile, double-buffered LDS,
// counted vmcnt across raw barriers) + (QK^T)V linattn.
// B=256, FG=4, ANT=32, D=1024, H=16, DK=64. M = 32768 rows for every GEMM.
// Scale bookkeeping (all powers of 2, exact):
//   xh = x (fp16, scale 1); Q1,K1,V1 scale 1; att1 stored * 2^-4
//   X2h = X2 * 2^-4 (fp16, overwrites xh in place); Q2,K2,V2 stored * 2^-4
//   att2 stored * 2^-16; final out = 2^16 * acc + bias + 16 * X2h  (fp32)

#define MTOT 32768
#define DM 1024

using half8   = __attribute__((ext_vector_type(8))) _Float16;
using h2      = __attribute__((ext_vector_type(2))) _Float16;
using floatx4 = __attribute__((ext_vector_type(4))) float;

#define ACT_NONE 0
#define ACT_ELU1 1
#define REMAP_NONE 0
#define REMAP_A2F 1   // (b,fg,ant) -> (b,ant,fg)
#define REMAP_F2O 2   // (b,ant,fg) -> (b,fg,ant)

#define VMWAIT(n) asm volatile("s_waitcnt vmcnt(" #n ")" ::: "memory")
#define SBAR() do { __builtin_amdgcn_s_barrier(); \
                    __builtin_amdgcn_sched_barrier(0); } while (0)

__device__ __forceinline__ void gload16(const void* g, void* ldsp) {
  __builtin_amdgcn_global_load_lds(
      (const __attribute__((address_space(1))) unsigned int*)g,
      (__attribute__((address_space(3))) unsigned int*)ldsp, 16, 0, 0);
}

__device__ __forceinline__ float fdot2f(h2 a, h2 b, float c) {
#if __has_builtin(__builtin_amdgcn_fdot2)
  return __builtin_amdgcn_fdot2(a, b, c, false);
#else
  return fmaf((float)a[0], (float)b[0], fmaf((float)a[1], (float)b[1], c));
#endif
}

// ---------------- GEMM ----------------
// C = act(sin_s * (A @ Wt^T) + bias [+ rs*resid16]); rows remapped on store.
// A: [M][1024] fp16 K-major. Wt: [N][1024] fp16 K-major (pre-transposed W).
// 256x256 tile, BK=64, 512 threads (8 waves 2Mx4N, wave -> 128x64 = 8x4 frags).
// LDS: 2-slot double buffer, 64KB/slot (A 256x64 = 32KB, B 256x64 = 32KB),
// 128KB total -> 1 block/CU. Pipeline: at step t issue stage(t+1) (8 loads),
// s_waitcnt vmcnt(8) (next step's loads stay in flight; step t's complete),
// raw s_barrier, compute step t, raw s_barrier (frees slot (t+1)&1's old data).
// Rows are 128B = 8 x 16B slots; swizzle slot ^= row&7 via pre-swizzled global
// source (linear LDS dest) + XOR on the ds_read address; conflict-free.
template<int ACT, int REMAP, bool RES, bool OF32, bool OF16>
__global__ __launch_bounds__(512, 2) void gemm_k(
    const _Float16* __restrict__ A, const _Float16* __restrict__ W,
    const float* __restrict__ bias, const _Float16* __restrict__ resid,
    float rs, float* __restrict__ Cf, _Float16* __restrict__ Ch,
    float sin_s, float sout_s)
{
  __shared__ __align__(16) char lds[131072];  // 2 x (32KB A | 32KB B)

  const int t = threadIdx.x, w = t >> 6, l = t & 63;
  // XCD-aware bijective swizzle of the m-tile index (gridDim.x = 128, %8 == 0)
  const int bx = blockIdx.x;
  const int m0 = (((bx & 7) << 4) + (bx >> 3)) * 256;
  const int n0 = blockIdx.y * 256;
  const int lr = l & 15, ls = l >> 4;
  const int wrow = (w >> 2) * 128, wcol = (w & 3) * 64;

  // staging geometry: round i covers rows i*64 + (t>>3); lane slot = t&7;
  // global fetch k-slot = (t&7) ^ (row&7)  (row&7 == (t>>3)&7).
  const int trow = t >> 3;                       // 0..63
  const int tsk  = ((t & 7) ^ (trow & 7)) * 8;   // swizzled k offset (halves)

  // ds_read byte offsets within a slot (k-step-independent)
  int aoff[2][8], boff[2][4];
#pragma unroll
  for (int kk = 0; kk < 2; ++kk) {
#pragma unroll
    for (int m = 0; m < 8; ++m) {
      int ra = wrow + m * 16 + lr;               // 0..255
      aoff[kk][m] = ra * 128 + (((kk * 4 + ls) ^ (ra & 7)) << 4);
    }
#pragma unroll
    for (int n = 0; n < 4; ++n) {
      int rb = wcol + n * 16 + lr;               // 0..255
      boff[kk][n] = 32768 + rb * 128 + (((kk * 4 + ls) ^ (rb & 7)) << 4);
    }
  }

  floatx4 acc[8][4];
#pragma unroll
  for (int m = 0; m < 8; ++m)
#pragma unroll
    for (int n = 0; n < 4; ++n) acc[m][n] = (floatx4)0.f;

  auto stage = [&](int kt, int s) {  // 8 gload_lds per thread: A 4, B 4
    const int kb = kt * 64;
    char* const base = lds + s * 65536 + w * 1024;
#pragma unroll
    for (int i = 0; i < 4; ++i)
      gload16(A + (size_t)(m0 + i * 64 + trow) * DM + kb + tsk,
              base + i * 8192);
#pragma unroll
    for (int i = 0; i < 4; ++i)
      gload16(W + (size_t)(n0 + i * 64 + trow) * DM + kb + tsk,
              base + 32768 + i * 8192);
  };

  auto compute = [&](int s) {
    const char* Ab = lds + s * 65536;
#pragma unroll
    for (int kk = 0; kk < 2; ++kk) {
      half8 af[8], bf[4];
#pragma unroll
      for (int m = 0; m < 8; ++m) af[m] = *(const half8*)(Ab + aoff[kk][m]);
#pragma unroll
      for (int n = 0; n < 4; ++n) bf[n] = *(const half8*)(Ab + boff[kk][n]);
      __builtin_amdgcn_s_setprio(1);
#pragma unroll
      for (int m = 0; m < 8; ++m)
#pragma unroll
        for (int n = 0; n < 4; ++n)
          acc[m][n] =
              __builtin_amdgcn_mfma_f32_16x16x32_f16(af[m], bf[n], acc[m][n], 0, 0, 0);
      __builtin_amdgcn_s_setprio(0);
    }
  };

  // prologue: stage K-step 0; main: K = 1024 -> 16 K-steps
  stage(0, 0);
  for (int t2 = 0; t2 < 15; ++t2) {
    stage(t2 + 1, (t2 + 1) & 1);
    VMWAIT(8);    // step t2's 8 loads complete; step t2+1's stay in flight
    SBAR();
    compute(t2 & 1);
    SBAR();       // all reads of slot (t2+1)&1's OLD data done before restage
  }
  VMWAIT(0);
  SBAR();
  compute(1);

  // hoist bias (4 distinct values per thread)
  float bb[4];
#pragma unroll
  for (int n = 0; n < 4; ++n) bb[n] = bias[n0 + wcol + n * 16 + lr];

  // epilogue phase 1: finalize values in acc (C/D map: row=(l>>4)*4+j, col=l&15)
#pragma unroll
  for (int m = 0; m < 8; ++m)
#pragma unroll
    for (int n = 0; n < 4; ++n)
#pragma unroll
      for (int j = 0; j < 4; ++j) {
        int rt = wrow + m * 16 + ls * 4 + j;
        int ct = wcol + n * 16 + lr;
        float v = acc[m][n][j] * sin_s + bb[n];
        if (RES) v += rs * (float)resid[(size_t)(m0 + rt) * DM + n0 + ct];
        if (ACT == ACT_ELU1) v = (v > 0.f) ? (v + 1.f) : expf(v);
        acc[m][n][j] = v;
      }
  // order all resid reads before any (possibly in-place, row-permuted) store
  if (RES && REMAP != REMAP_NONE) __syncthreads();

#pragma unroll
  for (int m = 0; m < 8; ++m)
#pragma unroll
    for (int n = 0; n < 4; ++n)
#pragma unroll
      for (int j = 0; j < 4; ++j) {
        int rt = wrow + m * 16 + ls * 4 + j;
        int ct = wcol + n * 16 + lr;
        int mg = m0 + rt, ng = n0 + ct;
        int srw;
        if (REMAP == REMAP_NONE) {
          srw = mg;
        } else if (REMAP == REMAP_A2F) {
          int b = mg >> 7, fg = (mg >> 5) & 3, ant = mg & 31;
          srw = b * 128 + ant * 4 + fg;
        } else {
          int b = mg >> 7, ant = (mg >> 2) & 31, fg = mg & 3;
          srw = b * 128 + fg * 32 + ant;
        }
        float v = acc[m][n][j];
        if (OF32) Cf[(size_t)srw * DM + ng] = v;
        if (OF16) Ch[(size_t)srw * DM + ng] = (_Float16)(v * sout_s);
      }
}

// ---------------- stage-1 linattn: L=32, one block per (g,h) ----------------
__global__ __launch_bounds__(256) void linattn32_k(
    _Float16* __restrict__ Q, const _Float16* __restrict__ K,
    const _Float16* __restrict__ V, float sout)
{
  __shared__ _Float16 Qs[32][64];   // swizzled: chunk ^= (row&7)*8
  __shared__ _Float16 Ks[32][64];   // swizzled: chunk ^= ((row>>2)&7)*8
  __shared__ _Float16 Vs[32][64];   // linear
  __shared__ float Ss[32][33];

  const int g = blockIdx.x, h = blockIdx.y;
  const size_t base = (size_t)g * 32 * DM + h * 64;
  const int t = threadIdx.x;

  {
    const int row = t >> 3, ch = (t & 7) * 8;
    half8 q8 = *(const half8*)(Q + base + (size_t)row * DM + ch);
    half8 k8 = *(const half8*)(K + base + (size_t)row * DM + ch);
    half8 v8 = *(const half8*)(V + base + (size_t)row * DM + ch);
    *(half8*)&Qs[row][ch ^ ((row & 7) * 8)] = q8;
    *(half8*)&Ks[row][ch ^ (((row >> 2) & 7) * 8)] = k8;
    *(half8*)&Vs[row][ch] = v8;
  }
  __syncthreads();

  {  // S[t][s] = Q[t] . K[s] ; thread -> (tt, 4 s's)
    const int tt = t >> 3, sg = t & 7;
    const int xq = (tt & 7) * 8, xk = sg * 8;
    float acc[4] = {};
#pragma unroll
    for (int jj = 0; jj < 32; ++jj) {
      h2 qq = *(const h2*)&Qs[tt][(2 * jj) ^ xq];
#pragma unroll
      for (int si = 0; si < 4; ++si) {
        h2 kk = *(const h2*)&Ks[sg * 4 + si][(2 * jj) ^ xk];
        acc[si] = fdot2f(qq, kk, acc[si]);
      }
    }
#pragma unroll
    for (int si = 0; si < 4; ++si) Ss[tt][sg * 4 + si] = acc[si];
  }
  __syncthreads();

  {  // att[t][e] = sum_s S[t][s] V[s][e] ; thread -> (tt, 8 e's)
    const int tt = t >> 3, e0 = (t & 7) * 8;
    float o[8] = {};
#pragma unroll
    for (int s = 0; s < 32; ++s) {
      float sv = Ss[tt][s];
      half8 vv = *(const half8*)&Vs[s][e0];
#pragma unroll
      for (int e = 0; e < 8; ++e) o[e] = fmaf(sv, (float)vv[e], o[e]);
    }
    half8 r;
#pragma unroll
    for (int e = 0; e < 8; ++e) r[e] = (_Float16)(o[e] * sout);
    *(half8*)(Q + base + (size_t)tt * DM + e0) = r;
  }
}

// ---------------- stage-2 linattn: L=4, one block per batch (16 heads) -------
__global__ __launch_bounds__(256) void linattn4_k(
    _Float16* __restrict__ Q, const _Float16* __restrict__ K,
    const _Float16* __restrict__ V, float sout)
{
  __shared__ _Float16 Qs[4][1024];  // per-head swizzle: chunk ^= (h&7)*8
  __shared__ _Float16 Ks[4][1024];
  __shared__ _Float16 Vs[4][1024];
  __shared__ float Ss[16][4][5];

  const int g = blockIdx.x;
  const size_t base = (size_t)g * 4 * DM;
  const int t = threadIdx.x;

  {
    const int off = t * 16;
    const int row = off >> 10, col = off & 1023;
    const int h = col >> 6, d = col & 63, x = (h & 7) * 8;
    const int c0 = h * 64 + (d ^ x), c1 = h * 64 + ((d + 8) ^ x);
    half8 q0 = *(const half8*)(Q + base + off);
    half8 q1 = *(const half8*)(Q + base + off + 8);
    half8 k0 = *(const half8*)(K + base + off);
    half8 k1 = *(const half8*)(K + base + off + 8);
    half8 v0 = *(const half8*)(V + base + off);
    half8 v1 = *(const half8*)(V + base + off + 8);
    *(half8*)&Qs[row][c0] = q0; *(half8*)&Qs[row][c1] = q1;
    *(half8*)&Ks[row][c0] = k0; *(half8*)&Ks[row][c1] = k1;
    *(half8*)&Vs[row][c0] = v0; *(half8*)&Vs[row][c1] = v1;
  }
  __syncthreads();

  {  // S[h][t][s]: one 64-dot per thread
    const int h = t >> 4, tt = (t >> 2) & 3, s = t & 3;
    const int x = (h & 7) * 8;
    const _Float16* qp = &Qs[tt][h * 64];
    const _Float16* kp = &Ks[s][h * 64];
    float acc = 0.f;
#pragma unroll
    for (int jj = 0; jj < 32; ++jj) {
      int dd = (2 * jj) ^ x;
      acc = fdot2f(*(const h2*)(qp + dd), *(const h2*)(kp + dd), acc);
    }
    Ss[h][tt][s] = acc;
  }
  __syncthreads();

  {  // att[t][h*64+e] = sum_s S[h][t][s] V[s][h*64+e] ; thread -> 16 cols
    const int tt = t >> 6, cg = t & 63;
    const int h = cg >> 2, e0 = (cg & 3) * 16, x = (h & 7) * 8;
    const float* sp = Ss[h][tt];
    float o[16] = {};
#pragma unroll
    for (int s = 0; s < 4; ++s) {
      float sv = sp[s];
      half8 va = *(const half8*)&Vs[s][h * 64 + (e0 ^ x)];
      half8 vb = *(const half8*)&Vs[s][h * 64 + ((e0 + 8) ^ x)];
#pragma unroll
      for (int e = 0; e < 8; ++e) {
        o[e]     = fmaf(sv, (float)va[e], o[e]);
        o[e + 8] = fmaf(sv, (float)vb[e], o[e + 8]);
      }
    }
    half8 r0, r1;
#pragma unroll
    for (int e = 0; e < 8; ++e) {
      r0[e] = (_Float16)(o[e] * sout);
      r1[e] = (_Float16)(o[e + 8] * sout);
    }
    _Float16* dst = Q + base + (size_t)tt * DM + h * 64 + e0;
    *(half8*)dst = r0;
    *(half8*)(dst + 8) = r1;
  }
}

// ---------------- small prep kernels ----------------
struct WPtrs { const float* p[8]; };

__global__ __launch_bounds__(256) void transpose_w8_k(
    WPtrs ws, _Float16* __restrict__ wt)
{
  __shared__ float tile[32][33];
  const float* W = ws.p[blockIdx.z];
  _Float16* Wt = wt + (size_t)DM * DM * blockIdx.z;
  const int tx = threadIdx.x & 31, ty = threadIdx.x >> 5;
  const int k0 = blockIdx.x * 32, n0 = blockIdx.y * 32;
#pragma unroll
  for (int r = 0; r < 4; ++r)
    tile[ty + r * 8][tx] = W[(size_t)(k0 + ty + r * 8) * DM + n0 + tx];
  __syncthreads();
#pragma unroll
  for (int r = 0; r < 4; ++r)
    Wt[(size_t)(n0 + ty + r * 8) * DM + k0 + tx] = (_Float16)tile[tx][ty + r * 8];
}

__global__ __launch_bounds__(256) void convf2h_k(
    const float* __restrict__ x, _Float16* __restrict__ xh, int n8)
{
  for (int i = blockIdx.x * blockDim.x + threadIdx.x; i < n8;
       i += gridDim.x * blockDim.x) {
    float4 a = ((const float4*)x)[i * 2];
    float4 b = ((const float4*)x)[i * 2 + 1];
    half8 h;
    h[0] = (_Float16)a.x; h[1] = (_Float16)a.y; h[2] = (_Float16)a.z; h[3] = (_Float16)a.w;
    h[4] = (_Float16)b.x; h[5] = (_Float16)b.y; h[6] = (_Float16)b.z; h[7] = (_Float16)b.w;
    ((half8*)xh)[i] = h;
  }
}

extern "C" void kernel_launch(void* const* d_in, const int* in_sizes, int n_in,
                              void* d_out, int out_size, void* d_ws, size_t ws_size,
                              hipStream_t stream)
{
  const float* x   = (const float*)d_in[0];
  WPtrs wp;
  for (int j = 0; j < 8; ++j) wp.p[j] = (const float*)d_in[1 + 2 * j];
  const float* aqb = (const float*)d_in[2];  const float* akb = (const float*)d_in[4];
  const float* avb = (const float*)d_in[6];  const float* aob = (const float*)d_in[8];
  const float* fqb = (const float*)d_in[10]; const float* fkb = (const float*)d_in[12];
  const float* fvb = (const float*)d_in[14]; const float* fob = (const float*)d_in[16];
  float* out = (float*)d_out;

  const size_t NE = (size_t)MTOT * DM;
  _Float16* xh = (_Float16*)d_ws;     // holds x, then X2h (in-place remap)
  _Float16* Qh = xh + NE;             // att overwrites Q in place
  _Float16* Kh = Qh + NE;
  _Float16* Vh = Kh + NE;
  _Float16* wt = Vh + NE;             // 8 x 1M halves
  const size_t WSZ = (size_t)DM * DM;

  dim3 gg(MTOT / 256, DM / 256), gb(512), sb(256);

  convf2h_k<<<2048, sb, 0, stream>>>(x, xh, (int)(NE / 8));
  transpose_w8_k<<<dim3(32, 32, 8), sb, 0, stream>>>(wp, wt);

  const float S = 0.0625f;  // 2^-4

  // ----- stage 1: antenna attention -----
  gemm_k<ACT_ELU1, REMAP_NONE, false, false, true><<<gg, gb, 0, stream>>>(
      xh, wt + WSZ * 0, aqb, nullptr, 0.f, nullptr, Qh, 1.f, 1.f);
  gemm_k<ACT_ELU1, REMAP_NONE, false, false, true><<<gg, gb, 0, stream>>>(
      xh, wt + WSZ * 1, akb, nullptr, 0.f, nullptr, Kh, 1.f, 1.f);
  gemm_k<ACT_NONE, REMAP_NONE, false, false, true><<<gg, gb, 0, stream>>>(
      xh, wt + WSZ * 2, avb, nullptr, 0.f, nullptr, Vh, 1.f, 1.f);
  linattn32_k<<<dim3(1024, 16), sb, 0, stream>>>(Qh, Kh, Vh, S);
  // X2h = (x + att1*2^4 @ Wout) * 2^-4, rows -> (b,ant,fg), in place over xh
  gemm_k<ACT_NONE, REMAP_A2F, true, false, true><<<gg, gb, 0, stream>>>(
      Qh, wt + WSZ * 3, aob, xh, 1.f, nullptr, xh, 16.f, S);

  // ----- stage 2: frequency attention -----
  gemm_k<ACT_ELU1, REMAP_NONE, false, false, true><<<gg, gb, 0, stream>>>(
      xh, wt + WSZ * 4, fqb, nullptr, 0.f, nullptr, Qh, 16.f, S);
  gemm_k<ACT_ELU1, REMAP_NONE, false, false, true><<<gg, gb, 0, stream>>>(
      xh, wt + WSZ * 5, fkb, nullptr, 0.f, nullptr, Kh, 16.f, S);
  gemm_k<ACT_NONE, REMAP_NONE, false, false, true><<<gg, gb, 0, stream>>>(
      xh, wt + WSZ * 6, fvb, nullptr, 0.f, nullptr, Vh, 16.f, S);
  linattn4_k<<<8192, sb, 0, stream>>>(Qh, Kh, Vh, S);
  // out = 2^16 * (att2 @ Wout2) + bias + 16*X2h, rows back to (b,fg,ant), fp32
  gemm_k<ACT_NONE, REMAP_F2O, true, true, false><<<gg, gb, 0, stream>>>(
      Qh, wt + WSZ * 7, fob, xh, 16.f, out, nullptr, 65536.f, 1.f);
}